// Round 12
// baseline (181.951 us; speedup 1.0000x reference)
//
#include <hip/hip_runtime.h>
#include <hip/hip_bf16.h>

#define NN 16384
#define NE 65536
#define NB 512          // mega grid: 512 blocks x 1024 threads, 2 blocks/CU

typedef __attribute__((ext_vector_type(8))) short short8;
typedef __attribute__((ext_vector_type(4))) float f32x4;

using bf16 = __hip_bfloat16;

__device__ __forceinline__ float b2f(bf16 v){ return __bfloat162float(v); }
__device__ __forceinline__ bf16 f2b(float v){ return __float2bfloat16(v); }

#define AADD(p,v)  __hip_atomic_fetch_add((p),(v),__ATOMIC_RELAXED,__HIP_MEMORY_SCOPE_AGENT)
#define ALOAD(p)   __hip_atomic_load((p),__ATOMIC_RELAXED,__HIP_MEMORY_SCOPE_AGENT)
#define ASTORE(p,v) __hip_atomic_store((p),(v),__ATOMIC_RELAXED,__HIP_MEMORY_SCOPE_AGENT)

struct MA {
    const float *x, *y, *rel, *a;
    const int *send, *recv;
    const float *W[4], *P[4];
    const float *bb[4], *bs[4], *bo[4], *bm[4], *bv[4];
    float* g;                 // [4][NE][16]
    unsigned *curs, *csr, *bar;
    bf16 *h1, *xo, *h3, *Bp, *xyc;
    float* outp;
};

// ============ flush barrier: arrive-all -> per-XCD wbl2 -> all-flushed
// ============                -> per-XCD inv -> per-XCD ready  (p = 1..4)
__device__ __forceinline__ void flushbar(unsigned* bar, int p){
    __syncthreads();                       // drains each wave's vmcnt
    if(threadIdx.x == 0){
        unsigned xcd = __builtin_amdgcn_s_getreg(63508) & 7u;  // HW_REG_XCC_ID
        // ---- stage A: 16-leaf tree arrival ----
        unsigned l = (unsigned)blockIdx.x & 15u;
        unsigned a = AADD(&bar[(p*16 + (int)l)*16], 1u);
        if(a == (NB/16 - 1u)){
            unsigned r = AADD(&bar[(80+p)*16], 1u);
            if(r == 15u) ASTORE(&bar[(88+p)*16], 1u);
        }
        while(ALOAD(&bar[(88+p)*16]) == 0u) __builtin_amdgcn_s_sleep(4);
        // ---- distinct-XCD count (pops registered at kernel entry) ----
        unsigned nx = 0;
        #pragma unroll
        for(int q=0;q<8;q++) nx += (ALOAD(&bar[(96+q)*16]) != 0u) ? 1u : 0u;
        // ---- stage B: elected per-XCD L2 writeback ----
        if(AADD(&bar[(104 + p*8 + (int)xcd)*16], 1u) == 0u){
            __builtin_amdgcn_fence(__ATOMIC_RELEASE, "agent");   // buffer_wbl2
            unsigned d = AADD(&bar[(144+p)*16], 1u);
            if(d == nx - 1u) ASTORE(&bar[(152+p)*16], 1u);
        }
        while(ALOAD(&bar[(152+p)*16]) == 0u) __builtin_amdgcn_s_sleep(4);
        // ---- stage D: elected per-XCD L2 invalidate ----
        if(AADD(&bar[(160 + p*8 + (int)xcd)*16], 1u) == 0u){
            __builtin_amdgcn_fence(__ATOMIC_ACQUIRE, "agent");   // buffer_inv
            ASTORE(&bar[(200 + (int)xcd)*16], (unsigned)p);
        }
        while(ALOAD(&bar[(200 + (int)xcd)*16]) < (unsigned)p) __builtin_amdgcn_s_sleep(4);
    }
    __syncthreads();
}

// ============ phase 0: countfill | tap softmax g | W pack | xyc ============
__device__ __forceinline__ void ph0(const MA& A){
    int gtid = blockIdx.x*1024 + threadIdx.x;    // [0, 524288)
    if(gtid < NE){
        int e = gtid;
        int rv = A.recv[e];
        unsigned pos = atomicAdd(&A.curs[rv], 1u);   // device-scope (m20)
        if(pos < 32u) A.csr[(unsigned)rv*32u + pos] = ((unsigned)e << 14) | (unsigned)A.send[e];
        return;
    }
    if(gtid < 327680){
        int task = gtid - NE;
        int e = task & (NE-1), c = task >> 16;
        float r0 = A.rel[e*3+0], r1 = A.rel[e*3+1], r2 = A.rel[e*3+2];
        float av = A.a[e];
        const float* P = A.P[c];
        float lg[16]; float mx = -1e30f;
        #pragma unroll
        for(int k=0;k<16;k++){
            float v = r0*P[k] + r1*P[16+k] + r2*P[32+k];
            lg[k] = v; mx = fmaxf(mx, v);
        }
        float ssum = 0.f;
        #pragma unroll
        for(int k=0;k<16;k++){ lg[k] = __expf(lg[k]-mx); ssum += lg[k]; }
        float inv = av/ssum;
        float* go = A.g + ((size_t)c*NE + e)*16;
        #pragma unroll
        for(int j=0;j<4;j++){
            ((float4*)go)[j] = make_float4(lg[j*4]*inv, lg[j*4+1]*inv,
                                           lg[j*4+2]*inv, lg[j*4+3]*inv);
        }
        return;
    }
    if(gtid < 348160){
        int t = gtid - 327680;
        const float* W; int Cout; int base; int tl;
        if(t < 8192)      { W=A.W[0]; Cout=64; base=0;     tl=t; }
        else if(t < 12288){ W=A.W[1]; Cout=32; base=8192;  tl=t-8192; }
        else if(t < 16384){ W=A.W[2]; Cout=64; base=12288; tl=t-12288; }
        else              { W=A.W[3]; Cout=32; base=16384; tl=t-16384; }
        int l  = tl & 63;
        int NCT = Cout >> 4;
        int ct = (tl >> 6) % NCT;
        int ks = (tl >> 6) / NCT;
        int col = ct*16 + (l & 15);
        int k0  = ks*32 + ((l >> 4) & 3)*8;
        short8 v;
        #pragma unroll
        for(int j=0;j<8;j++){
            bf16 h = f2b(W[(size_t)(k0+j)*Cout + col]);
            v[j] = (short)*(unsigned short*)&h;
        }
        ((short8*)A.Bp)[base + tl] = v;
        return;
    }
    if(gtid < 380928){
        int t = gtid - 348160;
        int n = t >> 1, half = t & 1;
        const float* src = half ? (A.y + n*32) : (A.x + n*32);
        bf16* dst = A.xyc + (size_t)n*64 + half*32;
        #pragma unroll
        for(int j=0;j<4;j++){
            float4 v0 = ((const float4*)src)[2*j];
            float4 v1 = ((const float4*)src)[2*j+1];
            short8 o; bf16 h;
            h = f2b(v0.x); o[0]=(short)*(unsigned short*)&h;
            h = f2b(v0.y); o[1]=(short)*(unsigned short*)&h;
            h = f2b(v0.z); o[2]=(short)*(unsigned short*)&h;
            h = f2b(v0.w); o[3]=(short)*(unsigned short*)&h;
            h = f2b(v1.x); o[4]=(short)*(unsigned short*)&h;
            h = f2b(v1.y); o[5]=(short)*(unsigned short*)&h;
            h = f2b(v1.z); o[6]=(short)*(unsigned short*)&h;
            h = f2b(v1.w); o[7]=(short)*(unsigned short*)&h;
            ((short8*)dst)[j] = o;
        }
    }
}

// ============ conv phase: 2 tiles, 1 node/wave, normal cached loads ========
template<int CIN, int NCT, int MODE, typename OT>
__device__ __forceinline__ void convp(
    char* sT, const bf16* __restrict__ fAb,
    const float* __restrict__ g,
    const unsigned* __restrict__ csr, const unsigned* __restrict__ curs,
    const bf16* __restrict__ Bp, const float* __restrict__ bias,
    const float* __restrict__ bns, const float* __restrict__ bno,
    const float* __restrict__ bnm, const float* __restrict__ bnv,
    const float* __restrict__ x, const float* __restrict__ y,
    OT* __restrict__ out)
{
    constexpr int KD   = CIN*16;
    constexpr int ROWB = KD*2;
    int wv = threadIdx.x >> 6, lane = threadIdx.x & 63;
    const int i     = (CIN==64) ? lane : (lane & 31);
    const int kbase = (CIN==64) ? 0 : ((lane >> 5) * 8);
    constexpr int KPL = (CIN==64) ? 16 : 8;

    for(int tile=0; tile<2; tile++){
        int nbase = (tile*NB + blockIdx.x)*16;
        int node  = nbase + wv;

        const unsigned* crow = csr + (unsigned)node*32u;
        unsigned cnt = curs[node]; if(cnt > 32u) cnt = 32u;
        uint4 c0 = ((const uint4*)crow)[0];
        uint4 c1 = ((const uint4*)crow)[1];
        unsigned uu[8] = {c0.x,c0.y,c0.z,c0.w, c1.x,c1.y,c1.z,c1.w};

        float acc[KPL];
        #pragma unroll
        for(int r=0;r<KPL;r++) acc[r] = 0.f;

        auto edge = [&](unsigned u){
            int sid = (int)(u & 16383u);
            int eid = (int)(u >> 14);
            float fe = b2f(fAb[sid*CIN + i]);
            const float4* gp = (const float4*)&g[(size_t)eid*16 + kbase];
            if(CIN==64){
                float4 g0=gp[0], g1=gp[1], g2=gp[2], g3=gp[3];
                acc[0]  += g0.x*fe; acc[1]  += g0.y*fe; acc[2]  += g0.z*fe; acc[3]  += g0.w*fe;
                acc[4]  += g1.x*fe; acc[5]  += g1.y*fe; acc[6]  += g1.z*fe; acc[7]  += g1.w*fe;
                acc[8]  += g2.x*fe; acc[9]  += g2.y*fe; acc[10] += g2.z*fe; acc[11] += g2.w*fe;
                acc[12] += g3.x*fe; acc[13] += g3.y*fe; acc[14] += g3.z*fe; acc[15] += g3.w*fe;
            } else {
                float4 g0=gp[0], g1=gp[1];
                acc[0] += g0.x*fe; acc[1] += g0.y*fe; acc[2] += g0.z*fe; acc[3] += g0.w*fe;
                acc[4] += g1.x*fe; acc[5] += g1.y*fe; acc[6] += g1.z*fe; acc[7] += g1.w*fe;
            }
        };
        #pragma unroll
        for(int j=0;j<8;j++){
            if((unsigned)j < cnt) edge(uu[j]);
        }
        for(unsigned j=8; j<cnt; j++) edge(crow[j]);

        unsigned xo_ = (unsigned)((wv & 7) << 4);
        if(CIN==64){
            #pragma unroll
            for(int k=0;k<16;k++){
                unsigned byte = (unsigned)wv*ROWB + ((((unsigned)(k*64 + lane))*2u) ^ xo_);
                *(bf16*)(sT + byte) = f2b(acc[k]);
            }
        } else {
            #pragma unroll
            for(int r=0;r<8;r++){
                unsigned byte = (unsigned)wv*ROWB + ((((unsigned)((kbase+r)*32 + i))*2u) ^ xo_);
                *(bf16*)(sT + byte) = f2b(acc[r]);
            }
        }
        __syncthreads();

        if(wv < NCT){
            int r = lane & 15, h = lane >> 4;
            int c = wv;
            const short8* Bp8 = (const short8*)Bp;
            f32x4 acc4 = (f32x4){0.f,0.f,0.f,0.f};
            unsigned xr = (unsigned)((r & 7) << 4);
            #pragma unroll 8
            for(int ks=0; ks<KD/32; ks++){
                unsigned ab = (unsigned)r*ROWB + (((unsigned)(ks*64 + h*16)) ^ xr);
                short8 af  = *(const short8*)(sT + ab);
                short8 bfr = Bp8[(ks*NCT + c)*64 + lane];
                acc4 = __builtin_amdgcn_mfma_f32_16x16x32_bf16(af, bfr, acc4, 0, 0, 0);
            }
            const int Cout = NCT*16;
            int col = c*16 + r;
            float inv = rsqrtf(bnv[col] + 1e-5f);
            float al  = bns[col] * inv;
            float be  = al*(bias[col] - bnm[col]) + bno[col];
            #pragma unroll
            for(int j=0;j<4;j++){
                int rr = nbase + h*4 + j;
                float v = al*acc4[j] + be;
                if(MODE==0){
                    out[(size_t)rr*Cout + col] = (OT)fmaxf(v, 0.f);
                } else {
                    float wei = 1.f/(1.f + __expf(-v));
                    float xv = x[rr*32 + col];
                    float yv = y[rr*32 + col];
                    out[(size_t)rr*32 + col] = (OT)(2.f*xv*wei + 2.f*yv*(1.f - wei));
                }
            }
        }
        __syncthreads();
    }
}

// ============ the mega kernel: 5 phases, 4 flush barriers ============
__global__ __launch_bounds__(1024, 8) void k_mega(MA A){
    __shared__ __align__(16) char sT[32768];
    if(threadIdx.x == 0){
        unsigned xcd = __builtin_amdgcn_s_getreg(63508) & 7u;
        AADD(&A.bar[(96 + (int)xcd)*16], 1u);      // XCD population census
    }
    ph0(A);
    flushbar(A.bar, 1);
    convp<64,4,0,bf16>(sT, A.xyc, A.g,                  A.csr, A.curs,
        A.Bp,                  A.bb[0],A.bs[0],A.bo[0],A.bm[0],A.bv[0], nullptr,nullptr, A.h1);
    flushbar(A.bar, 2);
    convp<64,2,1,bf16>(sT, A.h1, A.g + (size_t)1*NE*16, A.csr, A.curs,
        A.Bp + (size_t)8192*8, A.bb[1],A.bs[1],A.bo[1],A.bm[1],A.bv[1], A.x,A.y, A.xo);
    flushbar(A.bar, 3);
    convp<32,4,0,bf16>(sT, A.xo, A.g + (size_t)2*NE*16, A.csr, A.curs,
        A.Bp + (size_t)12288*8,A.bb[2],A.bs[2],A.bo[2],A.bm[2],A.bv[2], nullptr,nullptr, A.h3);
    flushbar(A.bar, 4);
    convp<64,2,1,float>(sT, A.h3, A.g + (size_t)3*NE*16, A.csr, A.curs,
        A.Bp + (size_t)16384*8,A.bb[3],A.bs[3],A.bo[3],A.bm[3],A.bv[3], A.x,A.y, A.outp);
}

// ============ launch: 2 graph nodes ============
extern "C" void kernel_launch(void* const* d_in, const int* in_sizes, int n_in,
                              void* d_out, int out_size, void* d_ws, size_t ws_size,
                              hipStream_t stream){
    MA A;
    A.x    = (const float*)d_in[0];
    A.y    = (const float*)d_in[1];
    A.send = (const int*)d_in[2];
    A.recv = (const int*)d_in[3];
    A.rel  = (const float*)d_in[4];
    A.a    = (const float*)d_in[5];
    for(int i=0;i<4;i++){
        int base = 6 + i*7;
        A.W[i]  = (const float*)d_in[base+0];
        A.P[i]  = (const float*)d_in[base+1];
        A.bb[i] = (const float*)d_in[base+2];
        A.bs[i] = (const float*)d_in[base+3];
        A.bo[i] = (const float*)d_in[base+4];
        A.bm[i] = (const float*)d_in[base+5];
        A.bv[i] = (const float*)d_in[base+6];
    }
    char* w = (char*)d_ws;
    A.g    = (float*)(w);                      // 16,777,216
    A.curs = (unsigned*)(w + 16777216);        //     65,536
    A.bar  = (unsigned*)(w + 16842752);        //     16,384
    A.csr  = (unsigned*)(w + 16859136);        //  2,097,152
    A.h1   = (bf16*)(w + 18956288);            //  2,097,152
    A.xo   = (bf16*)(w + 21053440);            //  1,048,576
    A.h3   = (bf16*)(w + 22102016);            //  2,097,152
    A.Bp   = (bf16*)(w + 24199168);            //    327,680
    A.xyc  = (bf16*)(w + 24526848);            //  2,097,152
    A.outp = (float*)d_out;

    // zero curs + barrier state (one node)
    hipMemsetAsync(w + 16777216, 0, 65536 + 16384, stream);
    k_mega<<<NB, 1024, 0, stream>>>(A);
}

// Round 13
// 120.982 us; speedup vs baseline: 1.5040x; 1.5040x over previous
//
#include <hip/hip_runtime.h>
#include <hip/hip_bf16.h>

#define NN 16384
#define NE 65536

typedef __attribute__((ext_vector_type(8))) short short8;
typedef __attribute__((ext_vector_type(4))) float f32x4;

using bf16 = __hip_bfloat16;

__device__ __forceinline__ float b2f(bf16 v){ return __bfloat162float(v); }
__device__ __forceinline__ bf16 f2b(float v){ return __float2bfloat16(v); }

// ================= k_setup: ONE kernel, no pre-zeroed memory ================
// blocks [0,32):    CSR partition build (LDS histogram, 512 nodes/block)
// blocks [32,288):  tap softmax g, all 4 convs (task = (b-32)*1024+tid)
// blocks [288,308): W pack into MFMA B-fragment order
// blocks [308,340): xyc[n][64] bf16 = [x[n] | y[n]]
__global__ __launch_bounds__(1024) void k_setup(
    const int* __restrict__ recv, const int* __restrict__ send,
    unsigned* __restrict__ curs, unsigned* __restrict__ csr,
    const float* __restrict__ rel, const float* __restrict__ a,
    const float* __restrict__ P1, const float* __restrict__ P2,
    const float* __restrict__ P3, const float* __restrict__ P4,
    float* __restrict__ g,
    const float* __restrict__ W1, const float* __restrict__ W2,
    const float* __restrict__ W3, const float* __restrict__ W4,
    bf16* __restrict__ Bp,
    const float* __restrict__ x, const float* __restrict__ y,
    bf16* __restrict__ xyc)
{
    __shared__ unsigned lcnt[512];
    int b = blockIdx.x, tid = threadIdx.x;

    if(b < 32){
        // ---- CSR partition: this block owns nodes [b*512, b*512+512) ----
        int nb = b*512;
        if(tid < 512) lcnt[tid] = 0u;
        __syncthreads();
        #pragma unroll 4
        for(int j=0; j<64; j++){
            int e  = j*1024 + tid;
            int rv = recv[e];
            int lr = rv - nb;
            if((unsigned)lr < 512u){
                unsigned pos = atomicAdd(&lcnt[lr], 1u);
                if(pos < 32u)
                    csr[(unsigned)rv*32u + pos] = ((unsigned)e << 14) | (unsigned)send[e];
            }
        }
        __syncthreads();
        if(tid < 512) curs[nb + tid] = lcnt[tid];
        return;
    }
    if(b < 288){
        // ---- tap softmax g ----
        int task = (b-32)*1024 + tid;        // [0, 262144)
        int e = task & (NE-1), c = task >> 16;
        float r0 = rel[e*3+0], r1 = rel[e*3+1], r2 = rel[e*3+2];
        float av = a[e];
        const float* P = (c==0)?P1:(c==1)?P2:(c==2)?P3:P4;
        float lg[16]; float mx = -1e30f;
        #pragma unroll
        for(int k=0;k<16;k++){
            float v = r0*P[k] + r1*P[16+k] + r2*P[32+k];
            lg[k] = v; mx = fmaxf(mx, v);
        }
        float ssum = 0.f;
        #pragma unroll
        for(int k=0;k<16;k++){ lg[k] = __expf(lg[k]-mx); ssum += lg[k]; }
        float inv = av/ssum;
        float* go = &g[((size_t)c*NE + e)*16];
        #pragma unroll
        for(int j=0;j<4;j++){
            ((float4*)go)[j] = make_float4(lg[j*4]*inv, lg[j*4+1]*inv,
                                           lg[j*4+2]*inv, lg[j*4+3]*inv);
        }
        return;
    }
    if(b < 308){
        // ---- W pack ----
        int t = (b-288)*1024 + tid;          // [0, 20480)
        const float* W; int Cout; int base; int tl;
        if(t < 8192)      { W=W1; Cout=64; base=0;     tl=t; }
        else if(t < 12288){ W=W2; Cout=32; base=8192;  tl=t-8192; }
        else if(t < 16384){ W=W3; Cout=64; base=12288; tl=t-12288; }
        else              { W=W4; Cout=32; base=16384; tl=t-16384; }
        int l  = tl & 63;
        int NCT = Cout >> 4;
        int ct = (tl >> 6) % NCT;
        int ks = (tl >> 6) / NCT;
        int col = ct*16 + (l & 15);
        int k0  = ks*32 + ((l >> 4) & 3)*8;
        short8 v;
        #pragma unroll
        for(int j=0;j<8;j++){
            bf16 h = f2b(W[(size_t)(k0+j)*Cout + col]);
            v[j] = (short)*(unsigned short*)&h;
        }
        ((short8*)Bp)[base + tl] = v;
        return;
    }
    // ---- xyc ----
    int t = (b-308)*1024 + tid;              // [0, 32768)
    int n = t >> 1, half = t & 1;
    const float* src = half ? (y + n*32) : (x + n*32);
    bf16* dst = xyc + (size_t)n*64 + half*32;
    #pragma unroll
    for(int j=0;j<4;j++){
        float4 v0 = ((const float4*)src)[2*j];
        float4 v1 = ((const float4*)src)[2*j+1];
        short8 o; bf16 h;
        h = f2b(v0.x); o[0]=(short)*(unsigned short*)&h;
        h = f2b(v0.y); o[1]=(short)*(unsigned short*)&h;
        h = f2b(v0.z); o[2]=(short)*(unsigned short*)&h;
        h = f2b(v0.w); o[3]=(short)*(unsigned short*)&h;
        h = f2b(v1.x); o[4]=(short)*(unsigned short*)&h;
        h = f2b(v1.y); o[5]=(short)*(unsigned short*)&h;
        h = f2b(v1.z); o[6]=(short)*(unsigned short*)&h;
        h = f2b(v1.w); o[7]=(short)*(unsigned short*)&h;
        ((short8*)dst)[j] = o;
    }
}

// ================= fused conv: wave-per-node agg -> LDS -> MFMA -> epilogue ===
// (R5-proven shape: 1024 thr = 16 waves = 16 nodes, 8-deep predicated unroll)
template<int CIN, int NCT, int MODE, typename OT>
__global__ __launch_bounds__(1024, 4) void k_conv(
    const bf16* __restrict__ fAb,
    const float* __restrict__ g,
    const unsigned* __restrict__ csr, const unsigned* __restrict__ curs,
    const bf16* __restrict__ Bp, const float* __restrict__ bias,
    const float* __restrict__ bns, const float* __restrict__ bno,
    const float* __restrict__ bnm, const float* __restrict__ bnv,
    const float* __restrict__ x, const float* __restrict__ y,
    OT* __restrict__ out)
{
    constexpr int KD   = CIN*16;
    constexpr int ROWB = KD*2;
    __shared__ __align__(16) char sT[16*ROWB];
    int wv = threadIdx.x >> 6, lane = threadIdx.x & 63;
    int nbase = blockIdx.x*16;
    int node  = nbase + wv;

    // ---------- aggregation (one node per wave) ----------
    const int i     = (CIN==64) ? lane : (lane & 31);
    const int kbase = (CIN==64) ? 0 : ((lane >> 5) * 8);
    unsigned cnt = curs[node]; if(cnt > 32u) cnt = 32u;
    const unsigned* crow = csr + (unsigned)node*32u;
    uint4 ca = ((const uint4*)crow)[0];
    uint4 cb = ((const uint4*)crow)[1];
    unsigned uu[8] = {ca.x, ca.y, ca.z, ca.w, cb.x, cb.y, cb.z, cb.w};

    constexpr int KPL = (CIN==64) ? 16 : 8;
    float acc[KPL];
    #pragma unroll
    for(int r=0;r<KPL;r++) acc[r] = 0.f;

    auto edge = [&](unsigned u){
        int sid = (int)(u & 16383u);
        int eid = (int)(u >> 14);
        float fe = b2f(fAb[sid*CIN + i]);
        const float4* gp = (const float4*)&g[(size_t)eid*16 + kbase];
        if(CIN==64){
            float4 g0=gp[0], g1=gp[1], g2=gp[2], g3=gp[3];
            acc[0]  += g0.x*fe; acc[1]  += g0.y*fe; acc[2]  += g0.z*fe; acc[3]  += g0.w*fe;
            acc[4]  += g1.x*fe; acc[5]  += g1.y*fe; acc[6]  += g1.z*fe; acc[7]  += g1.w*fe;
            acc[8]  += g2.x*fe; acc[9]  += g2.y*fe; acc[10] += g2.z*fe; acc[11] += g2.w*fe;
            acc[12] += g3.x*fe; acc[13] += g3.y*fe; acc[14] += g3.z*fe; acc[15] += g3.w*fe;
        } else {
            float4 g0=gp[0], g1=gp[1];
            acc[0] += g0.x*fe; acc[1] += g0.y*fe; acc[2] += g0.z*fe; acc[3] += g0.w*fe;
            acc[4] += g1.x*fe; acc[5] += g1.y*fe; acc[6] += g1.z*fe; acc[7] += g1.w*fe;
        }
    };
    #pragma unroll
    for(int j=0;j<8;j++){
        if((unsigned)j < cnt) edge(uu[j]);
    }
    for(unsigned j=8; j<cnt; j++) edge(crow[j]);

    // ---------- LDS write (swizzled) ----------
    unsigned xo_ = (unsigned)((wv & 7) << 4);
    if(CIN==64){
        #pragma unroll
        for(int k=0;k<16;k++){
            unsigned byte = (unsigned)wv*ROWB + ((((unsigned)(k*64 + lane))*2u) ^ xo_);
            *(bf16*)(sT + byte) = f2b(acc[k]);
        }
    } else {
        #pragma unroll
        for(int r=0;r<8;r++){
            unsigned byte = (unsigned)wv*ROWB + ((((unsigned)((kbase+r)*32 + i))*2u) ^ xo_);
            *(bf16*)(sT + byte) = f2b(acc[r]);
        }
    }
    __syncthreads();

    // ---------- GEMM from LDS (waves 0..NCT-1, full K) ----------
    if(wv >= NCT) return;
    int r = lane & 15, h = lane >> 4;
    int c = wv;
    const short8* Bp8 = (const short8*)Bp;
    f32x4 acc4 = (f32x4){0.f,0.f,0.f,0.f};
    unsigned xr = (unsigned)((r & 7) << 4);
    #pragma unroll 8
    for(int ks=0; ks<KD/32; ks++){
        unsigned ab = (unsigned)r*ROWB + (((unsigned)(ks*64 + h*16)) ^ xr);
        short8 af  = *(const short8*)(sT + ab);
        short8 bfr = Bp8[(ks*NCT + c)*64 + lane];
        acc4 = __builtin_amdgcn_mfma_f32_16x16x32_bf16(af, bfr, acc4, 0, 0, 0);
    }

    // ---------- epilogue ----------
    const int Cout = NCT*16;
    int col = c*16 + r;
    float inv = rsqrtf(bnv[col] + 1e-5f);
    float al  = bns[col] * inv;
    float be  = al*(bias[col] - bnm[col]) + bno[col];
    #pragma unroll
    for(int j=0;j<4;j++){
        int rr = nbase + h*4 + j;
        float v = al*acc4[j] + be;
        if(MODE==0){
            out[(size_t)rr*Cout + col] = (OT)fmaxf(v, 0.f);
        } else {
            float wei = 1.f/(1.f + __expf(-v));
            float xv = x[rr*32 + col];
            float yv = y[rr*32 + col];
            out[(size_t)rr*32 + col] = (OT)(2.f*xv*wei + 2.f*yv*(1.f - wei));
        }
    }
}

// ================= launch: 5 graph nodes =================
extern "C" void kernel_launch(void* const* d_in, const int* in_sizes, int n_in,
                              void* d_out, int out_size, void* d_ws, size_t ws_size,
                              hipStream_t stream){
    const float* x   = (const float*)d_in[0];
    const float* y   = (const float*)d_in[1];
    const int* send  = (const int*)d_in[2];
    const int* recv  = (const int*)d_in[3];
    const float* rel = (const float*)d_in[4];
    const float* a   = (const float*)d_in[5];
    const float *W[4], *P[4], *bb[4], *bs[4], *bo[4], *bm[4], *bv[4];
    for(int i=0;i<4;i++){
        int base = 6 + i*7;
        W[i]  = (const float*)d_in[base+0];
        P[i]  = (const float*)d_in[base+1];
        bb[i] = (const float*)d_in[base+2];
        bs[i] = (const float*)d_in[base+3];
        bo[i] = (const float*)d_in[base+4];
        bm[i] = (const float*)d_in[base+5];
        bv[i] = (const float*)d_in[base+6];
    }
    char* w = (char*)d_ws;
    float*    g    = (float*)(w);                   // 16,777,216 B
    unsigned* curs = (unsigned*)(w + 16777216);     //     65,536 B
    unsigned* csr  = (unsigned*)(w + 16842752);     //  2,097,152 B
    bf16*     h1   = (bf16*)(w + 18939904);         //  2,097,152 B
    bf16*     xo   = (bf16*)(w + 21037056);         //  1,048,576 B
    bf16*     h3   = (bf16*)(w + 22085632);         //  2,097,152 B
    bf16*     Bp   = (bf16*)(w + 24182784);         //    327,680 B
    bf16*     xyc  = (bf16*)(w + 24510464);         //  2,097,152 B
    float*    outp = (float*)d_out;

    k_setup<<<340, 1024, 0, stream>>>(recv, send, curs, csr, rel, a,
                                      P[0], P[1], P[2], P[3], g,
                                      W[0], W[1], W[2], W[3], Bp,
                                      x, y, xyc);

    // conv1: xyc -> h1 (BN+relu)
    (k_conv<64,4,0,bf16>) <<<NN/16, 1024, 0, stream>>>(xyc, g + (size_t)0*NE*16, csr, curs,
        Bp + (size_t)0*8,     bb[0], bs[0], bo[0], bm[0], bv[0], nullptr, nullptr, h1);
    // conv2: h1 -> wei1 -> xo (AFF)
    (k_conv<64,2,1,bf16>) <<<NN/16, 1024, 0, stream>>>(h1, g + (size_t)1*NE*16, csr, curs,
        Bp + (size_t)8192*8,  bb[1], bs[1], bo[1], bm[1], bv[1], x, y, xo);
    // conv3: xo -> h3 (BN+relu)
    (k_conv<32,4,0,bf16>) <<<NN/16, 1024, 0, stream>>>(xo, g + (size_t)2*NE*16, csr, curs,
        Bp + (size_t)12288*8, bb[2], bs[2], bo[2], bm[2], bv[2], nullptr, nullptr, h3);
    // conv4: h3 -> wei2 -> out (AFF, f32)
    (k_conv<64,2,1,float>)<<<NN/16, 1024, 0, stream>>>(h3, g + (size_t)3*NE*16, csr, curs,
        Bp + (size_t)16384*8, bb[3], bs[3], bo[3], bm[3], bv[3], x, y, outp);
}